// Round 8
// baseline (154.849 us; speedup 1.0000x reference)
//
#include <hip/hip_runtime.h>

#define NNODES 50000
#define NEDGES 200000
#define DDIM 512

typedef __attribute__((ext_vector_type(8))) short bf16x8;
typedef __attribute__((ext_vector_type(4))) float f32x4;

static __device__ __forceinline__ unsigned short f2bf(float f) {
  unsigned u = __float_as_uint(f);
  unsigned r = (u + 0x7fffu + ((u >> 16) & 1u)) >> 16;  // RNE
  return (unsigned short)r;
}

static __device__ __forceinline__ void gload_lds16(const void* g, void* l) {
  __builtin_amdgcn_global_load_lds(
      (const __attribute__((address_space(1))) unsigned int*)g,
      (__attribute__((address_space(3))) unsigned int*)l, 16, 0, 0);
}

// ---------------------------------------------------------------------------
// Wt[n][k] = bf16(W[k][n])  (512x512 transpose via LDS) + zero deg[]
// (deg zeroing rides here to avoid a hipMemsetAsync graph node that
//  profiled at 57.8 us; this kernel runs before hist_kernel in-stream.)
// ---------------------------------------------------------------------------
__global__ __launch_bounds__(256) void cvt_wt_kernel(
    const float* __restrict__ W, unsigned short* __restrict__ Wt,
    int* __restrict__ deg) {
  const int gid = (blockIdx.x + blockIdx.y * gridDim.x) * 256 + threadIdx.x;
  if (gid < NNODES) deg[gid] = 0;

  __shared__ float t[32][33];
  const int n0 = blockIdx.x * 32, k0 = blockIdx.y * 32;
  const int tx = threadIdx.x & 31, ty = threadIdx.x >> 5;  // ty 0..7
  for (int r = ty; r < 32; r += 8)
    t[r][tx] = W[(size_t)(k0 + r) * DDIM + n0 + tx];
  __syncthreads();
  for (int r = ty; r < 32; r += 8)
    Wt[(size_t)(n0 + r) * DDIM + k0 + tx] = f2bf(t[tx][r]);
}

// ---------------------------------------------------------------------------
// MFMA GEMM: C_bf16[M,512] = bf16(A_f32[M,512]) @ Wt_bf16[512,512]^T + bias
// 128x128 tile, BK=32, 4 waves (2x2), 16x16x32 MFMA.
// A: reg-staged fp32 -> in-register bf16 cvt -> ds_write_b128 (fuses cvt_h).
// B: global_load_lds. 2-phase double buffer; A-loads issued before COMPUTE,
// A ds_writes after (T14 split — HBM latency hides under MFMA).
// Both-sides XOR swizzle; XCD-chunked block swizzle; LDS-staged epilogue.
// ---------------------------------------------------------------------------
__global__ __launch_bounds__(256) void gemm_mfma_kernel(
    const float* __restrict__ A, const unsigned short* __restrict__ Bt,
    const float* __restrict__ bias, unsigned short* __restrict__ C, int M) {
  __shared__ unsigned short As[2][128 * 32];
  __shared__ unsigned short Bs[2][128 * 32];
  const int tid = threadIdx.x;
  const int wid = tid >> 6, lane = tid & 63;

  // bijective XCD-chunked remap (8 XCDs)
  const int nwg = gridDim.x;
  const int q = nwg >> 3, rr = nwg & 7;
  const int x = blockIdx.x & 7, idx = blockIdx.x >> 3;
  const int wg = x * q + min(x, rr) + idx;

  const int mt = wg >> 2, nt = wg & 3;
  const int bm = mt * 128, bn = nt * 128;
  const int wr = wid >> 1, wc = wid & 1;

  f32x4 acc[4][4] = {};

  // staging: slot = tid; row = tid>>2 within half, swizzled col group
  const int r0 = tid >> 2;
  const int cge = (tid & 3) ^ ((r0 >> 1) & 3);

  const int arow0 = min(bm + r0, M - 1);
  const int arow1 = min(bm + r0 + 64, M - 1);

  const float* ha0 = A + (size_t)arow0 * DDIM + cge * 8;  // fp32 source
  const float* ha1 = A + (size_t)arow1 * DDIM + cge * 8;
  const unsigned short* b0 = Bt + (size_t)(bn + r0) * DDIM + cge * 8;
  const unsigned short* b1 = Bt + (size_t)(bn + r0 + 64) * DDIM + cge * 8;

  const int l16 = lane & 15, lk = lane >> 4;
  const int lke = lk ^ ((l16 >> 1) & 3);  // swizzled read k-group

  // wave-uniform LDS staging bases for B (ushort offsets)
  const int sOff0 = (wid * 64) * 8;
  const int sOff1 = (256 + wid * 64) * 8;

  float4 ra00, ra01, ra10, ra11;  // A fp32 in flight (8 floats per half)

#define STAGE_A_LOAD(kf)                           \
  do {                                             \
    ra00 = *(const float4*)(ha0 + (kf));           \
    ra01 = *(const float4*)(ha0 + (kf) + 4);       \
    ra10 = *(const float4*)(ha1 + (kf));           \
    ra11 = *(const float4*)(ha1 + (kf) + 4);       \
  } while (0)

#define STAGE_A_WRITE(buf)                                              \
  do {                                                                  \
    uint4 p0, p1;                                                       \
    p0.x = (unsigned)f2bf(ra00.x) | ((unsigned)f2bf(ra00.y) << 16);     \
    p0.y = (unsigned)f2bf(ra00.z) | ((unsigned)f2bf(ra00.w) << 16);     \
    p0.z = (unsigned)f2bf(ra01.x) | ((unsigned)f2bf(ra01.y) << 16);     \
    p0.w = (unsigned)f2bf(ra01.z) | ((unsigned)f2bf(ra01.w) << 16);     \
    p1.x = (unsigned)f2bf(ra10.x) | ((unsigned)f2bf(ra10.y) << 16);     \
    p1.y = (unsigned)f2bf(ra10.z) | ((unsigned)f2bf(ra10.w) << 16);     \
    p1.z = (unsigned)f2bf(ra11.x) | ((unsigned)f2bf(ra11.y) << 16);     \
    p1.w = (unsigned)f2bf(ra11.z) | ((unsigned)f2bf(ra11.w) << 16);     \
    *(uint4*)&As[buf][(size_t)tid * 8] = p0;                            \
    *(uint4*)&As[buf][(size_t)(256 + tid) * 8] = p1;                    \
  } while (0)

#define STAGE_B(buf, k0)                      \
  do {                                        \
    gload_lds16(b0 + (k0), &Bs[buf][sOff0]);  \
    gload_lds16(b1 + (k0), &Bs[buf][sOff1]);  \
  } while (0)

#define COMPUTE(buf)                                                          \
  do {                                                                        \
    bf16x8 af[4], bfr[4];                                                     \
    _Pragma("unroll") for (int i = 0; i < 4; ++i) {                           \
      af[i]  = *(const bf16x8*)&As[buf][(wr * 64 + i * 16 + l16) * 32 + lke * 8]; \
      bfr[i] = *(const bf16x8*)&Bs[buf][(wc * 64 + i * 16 + l16) * 32 + lke * 8]; \
    }                                                                         \
    _Pragma("unroll") for (int i = 0; i < 4; ++i)                             \
        _Pragma("unroll") for (int j = 0; j < 4; ++j)                         \
            acc[i][j] = __builtin_amdgcn_mfma_f32_16x16x32_bf16(              \
                af[i], bfr[j], acc[i][j], 0, 0, 0);                           \
  } while (0)

  // prologue: tile 0
  STAGE_A_LOAD(0);
  STAGE_B(0, 0);
  STAGE_A_WRITE(0);
  __syncthreads();

#pragma unroll 2
  for (int t = 0; t < 15; ++t) {
    const int cur = t & 1;
    STAGE_A_LOAD((t + 1) * 32);   // fp32 global loads -> regs (issued early)
    STAGE_B(cur ^ 1, (t + 1) * 32);
    COMPUTE(cur);
    STAGE_A_WRITE(cur ^ 1);       // cvt + ds_write (waits vm under MFMA)
    __syncthreads();
  }
  COMPUTE(1);       // tile 15 lives in buf 1
  __syncthreads();  // LDS about to be reused as epilogue scratch

  // ---- Epilogue: per-wave 64x64 bf16 tile staged in LDS, coalesced stores.
  unsigned short* cl = (wid < 2) ? &As[0][0] + wid * 4096
                                 : &Bs[0][0] + (wid - 2) * 4096;
#pragma unroll
  for (int j = 0; j < 4; ++j) {
    const float bv = bias[bn + wc * 64 + j * 16 + l16];
#pragma unroll
    for (int i = 0; i < 4; ++i)
#pragma unroll
      for (int qq = 0; qq < 4; ++qq)
        cl[(i * 16 + lk * 4 + qq) * 64 + j * 16 + l16] =
            f2bf(acc[i][j][qq] + bv);
  }
  __syncthreads();
#pragma unroll
  for (int pass = 0; pass < 8; ++pass) {
    const int rt = pass * 8 + (lane >> 3);   // row in 64x64 tile
    const int c0 = (lane & 7) * 8;           // col in 64x64 tile (8 cols/lane)
    const int grow = bm + wr * 64 + rt;
    if (grow < M) {
      const uint4 v = *(const uint4*)&cl[rt * 64 + c0];
      *(uint4*)&C[(size_t)grow * DDIM + bn + wc * 64 + c0] = v;
    }
  }
#undef STAGE_A_LOAD
#undef STAGE_A_WRITE
#undef STAGE_B
#undef COMPUTE
}

// ---------------------------------------------------------------------------
// CSR build: histogram of dst
// ---------------------------------------------------------------------------
__global__ __launch_bounds__(256) void hist_kernel(const int* __restrict__ dst,
                                                   int* __restrict__ deg, int E) {
  const int e = blockIdx.x * 256 + threadIdx.x;
  if (e < E) atomicAdd(&deg[dst[e]], 1);
}

// ---------------------------------------------------------------------------
// Parallel 3-kernel exclusive scan over deg[0..n) -> off[0..n], cur[0..n)
// ---------------------------------------------------------------------------
__global__ __launch_bounds__(256) void chunk_sum_kernel(
    const int* __restrict__ deg, int* __restrict__ part, int n) {
  const int base = blockIdx.x * 1024;
  int v = 0;
  for (int i = threadIdx.x; i < 1024; i += 256) {
    const int idx = base + i;
    v += (idx < n) ? deg[idx] : 0;
  }
#pragma unroll
  for (int s = 32; s; s >>= 1) v += __shfl_down(v, s, 64);
  __shared__ int ws[4];
  if ((threadIdx.x & 63) == 0) ws[threadIdx.x >> 6] = v;
  __syncthreads();
  if (threadIdx.x == 0) part[blockIdx.x] = ws[0] + ws[1] + ws[2] + ws[3];
}

__global__ void scan_part_kernel(int* __restrict__ part, int nb) {
  const int lane = threadIdx.x & 63;
  int v = (lane < nb) ? part[lane] : 0;
  int incl = v;
#pragma unroll
  for (int s = 1; s < 64; s <<= 1) {
    int t = __shfl_up(incl, s, 64);
    if (lane >= s) incl += t;
  }
  if (lane < nb) part[lane] = incl - v;  // exclusive
}

__global__ __launch_bounds__(1024) void chunk_scan_kernel(
    const int* __restrict__ deg, const int* __restrict__ part,
    int* __restrict__ off, int* __restrict__ cur, int n) {
  __shared__ int wsum[16];
  const int tid = threadIdx.x, lane = tid & 63, wid = tid >> 6;
  const int i = blockIdx.x * 1024 + tid;
  const int v = (i < n) ? deg[i] : 0;
  int incl = v;
#pragma unroll
  for (int s = 1; s < 64; s <<= 1) {
    int t = __shfl_up(incl, s, 64);
    if (lane >= s) incl += t;
  }
  if (lane == 63) wsum[wid] = incl;
  __syncthreads();
  if (wid == 0 && lane < 16) {
    int wv = wsum[lane];
#pragma unroll
    for (int s = 1; s < 16; s <<= 1) {
      int t = __shfl_up(wv, s, 16);
      if (lane >= s) wv += t;
    }
    wsum[lane] = wv;
  }
  __syncthreads();
  const int add = part[blockIdx.x] + ((wid > 0) ? wsum[wid - 1] : 0);
  if (i < n) {
    off[i + 1] = add + incl;
    cur[i] = add + incl - v;
  }
  if (i == 0) off[0] = 0;
}

// ---------------------------------------------------------------------------
// CSR fill: slot per edge via per-dst cursor; pack (src, weight) as uint2.
// ---------------------------------------------------------------------------
__global__ __launch_bounds__(256) void fill_kernel(
    const int* __restrict__ src, const int* __restrict__ dst,
    const float* __restrict__ ew, int* __restrict__ cur,
    uint2* __restrict__ epair, int E) {
  const int e = blockIdx.x * 256 + threadIdx.x;
  if (e >= E) return;
  const int p = atomicAdd(&cur[dst[e]], 1);
  epair[p] = make_uint2((unsigned)src[e], __float_as_uint(ew[e]));
}

// ---------------------------------------------------------------------------
// Gather: one wave per node; 2-deep edge unroll; mean + relu; nontemporal
// row write (out is write-once — keep hp resident in L2/L3).
// ---------------------------------------------------------------------------
__global__ __launch_bounds__(256) void gather_kernel(
    const unsigned short* __restrict__ hp, const int* __restrict__ off,
    const uint2* __restrict__ epair, float* __restrict__ out, int n) {
  const int node = blockIdx.x * 4 + (threadIdx.x >> 6);
  if (node >= n) return;
  const int lane = threadIdx.x & 63;
  const int beg = off[node], end = off[node + 1];

  float acc[8] = {0.f, 0.f, 0.f, 0.f, 0.f, 0.f, 0.f, 0.f};
  int p = beg;
  for (; p + 2 <= end; p += 2) {
    const uint2 e0 = epair[p];
    const uint2 e1 = epair[p + 1];
    const float w0 = __uint_as_float(e0.y);
    const float w1 = __uint_as_float(e1.y);
    const uint4 u0 = *(const uint4*)(hp + (size_t)e0.x * DDIM + lane * 8);
    const uint4 u1 = *(const uint4*)(hp + (size_t)e1.x * DDIM + lane * 8);
    const unsigned a0[4] = {u0.x, u0.y, u0.z, u0.w};
    const unsigned a1[4] = {u1.x, u1.y, u1.z, u1.w};
#pragma unroll
    for (int qv = 0; qv < 4; ++qv) {
      acc[2 * qv + 0] += w0 * __uint_as_float(a0[qv] << 16) +
                         w1 * __uint_as_float(a1[qv] << 16);
      acc[2 * qv + 1] += w0 * __uint_as_float(a0[qv] & 0xffff0000u) +
                         w1 * __uint_as_float(a1[qv] & 0xffff0000u);
    }
  }
  if (p < end) {
    const uint2 e0 = epair[p];
    const float w0 = __uint_as_float(e0.y);
    const uint4 u0 = *(const uint4*)(hp + (size_t)e0.x * DDIM + lane * 8);
    const unsigned a0[4] = {u0.x, u0.y, u0.z, u0.w};
#pragma unroll
    for (int qv = 0; qv < 4; ++qv) {
      acc[2 * qv + 0] += w0 * __uint_as_float(a0[qv] << 16);
      acc[2 * qv + 1] += w0 * __uint_as_float(a0[qv] & 0xffff0000u);
    }
  }

  const float inv = 1.0f / fmaxf((float)(end - beg), 1.0f);
  f32x4 o0, o1;
  o0.x = fmaxf(acc[0] * inv, 0.f);
  o0.y = fmaxf(acc[1] * inv, 0.f);
  o0.z = fmaxf(acc[2] * inv, 0.f);
  o0.w = fmaxf(acc[3] * inv, 0.f);
  o1.x = fmaxf(acc[4] * inv, 0.f);
  o1.y = fmaxf(acc[5] * inv, 0.f);
  o1.z = fmaxf(acc[6] * inv, 0.f);
  o1.w = fmaxf(acc[7] * inv, 0.f);
  float* orow = out + (size_t)node * DDIM + lane * 8;
  __builtin_nontemporal_store(o0, (f32x4*)(orow + 0));
  __builtin_nontemporal_store(o1, (f32x4*)(orow + 4));
}

extern "C" void kernel_launch(void* const* d_in, const int* in_sizes, int n_in,
                              void* d_out, int out_size, void* d_ws, size_t ws_size,
                              hipStream_t stream) {
  const float* h  = (const float*)d_in[0];
  const float* W  = (const float*)d_in[1];
  const float* b  = (const float*)d_in[2];
  const float* ew = (const float*)d_in[3];
  const int* src  = (const int*)d_in[4];
  const int* dst  = (const int*)d_in[5];
  float* out = (float*)d_out;

  // Workspace: hp (bf16 h_proj), Wt, CSR arrays
  char* ws = (char*)d_ws;
  size_t o = 0;
  auto alloc = [&](size_t bytes) {
    char* p = ws + o;
    o += (bytes + 255) & ~(size_t)255;
    return p;
  };
  unsigned short* hp = (unsigned short*)alloc((size_t)NNODES * DDIM * 2);  // 51.2 MB
  unsigned short* Wt = (unsigned short*)alloc((size_t)DDIM * DDIM * 2);    // 0.5 MB
  int* deg    = (int*)alloc((size_t)NNODES * 4);
  int* off    = (int*)alloc((size_t)(NNODES + 1) * 4);
  int* cur    = (int*)alloc((size_t)NNODES * 4);
  uint2* epair = (uint2*)alloc((size_t)NEDGES * 8);
  int* part   = (int*)alloc(64 * 4);

  const int nchunks = (NNODES + 1023) / 1024;  // 49

  // 1) W transpose+cvt (also zeros deg[])
  dim3 wgrid(16, 16);
  cvt_wt_kernel<<<wgrid, 256, 0, stream>>>(W, Wt, deg);

  // 2) fused MFMA GEMM: hp = bf16(bf16(h) @ Wt^T + b)
  const int mtiles = (NNODES + 127) / 128;  // 391
  gemm_mfma_kernel<<<mtiles * 4, 256, 0, stream>>>(h, Wt, b, hp, NNODES);

  // 3) CSR build by dst (parallel scan)
  hist_kernel<<<(NEDGES + 255) / 256, 256, 0, stream>>>(dst, deg, NEDGES);
  chunk_sum_kernel<<<nchunks, 256, 0, stream>>>(deg, part, NNODES);
  scan_part_kernel<<<1, 64, 0, stream>>>(part, nchunks);
  chunk_scan_kernel<<<nchunks, 1024, 0, stream>>>(deg, part, off, cur, NNODES);
  fill_kernel<<<(NEDGES + 255) / 256, 256, 0, stream>>>(src, dst, ew, cur,
                                                        epair, NEDGES);

  // 4) Gather + mean + relu (one wave per node)
  gather_kernel<<<(NNODES + 3) / 4, 256, 0, stream>>>(hp, off, epair, out,
                                                      NNODES);
}

// Round 9
// 151.168 us; speedup vs baseline: 1.0244x; 1.0244x over previous
//
#include <hip/hip_runtime.h>

#define NNODES 50000
#define NEDGES 200000
#define DDIM 512

typedef __attribute__((ext_vector_type(8))) short bf16x8;
typedef __attribute__((ext_vector_type(4))) float f32x4;

static __device__ __forceinline__ unsigned short f2bf(float f) {
  unsigned u = __float_as_uint(f);
  unsigned r = (u + 0x7fffu + ((u >> 16) & 1u)) >> 16;  // RNE
  return (unsigned short)r;
}

static __device__ __forceinline__ void gload_lds16(const void* g, void* l) {
  __builtin_amdgcn_global_load_lds(
      (const __attribute__((address_space(1))) unsigned int*)g,
      (__attribute__((address_space(3))) unsigned int*)l, 16, 0, 0);
}

// ---------------------------------------------------------------------------
// Convert h (fp32) -> bf16, 8 elements/thread
// ---------------------------------------------------------------------------
__global__ __launch_bounds__(256) void cvt_h_kernel(
    const float* __restrict__ in, unsigned short* __restrict__ out, int n8) {
  for (int i = blockIdx.x * 256 + threadIdx.x; i < n8; i += gridDim.x * 256) {
    const float4 v0 = ((const float4*)in)[(size_t)i * 2];
    const float4 v1 = ((const float4*)in)[(size_t)i * 2 + 1];
    uint4 p;
    p.x = (unsigned)f2bf(v0.x) | ((unsigned)f2bf(v0.y) << 16);
    p.y = (unsigned)f2bf(v0.z) | ((unsigned)f2bf(v0.w) << 16);
    p.z = (unsigned)f2bf(v1.x) | ((unsigned)f2bf(v1.y) << 16);
    p.w = (unsigned)f2bf(v1.z) | ((unsigned)f2bf(v1.w) << 16);
    ((uint4*)out)[i] = p;
  }
}

// ---------------------------------------------------------------------------
// Wt[n][k] = bf16(W[k][n])  (512x512 transpose via LDS) + zero deg[]
// (deg zeroing rides here to avoid a hipMemsetAsync graph node that
//  profiled at 57.8 us; this kernel runs before hist_kernel in-stream.)
// ---------------------------------------------------------------------------
__global__ __launch_bounds__(256) void cvt_wt_kernel(
    const float* __restrict__ W, unsigned short* __restrict__ Wt,
    int* __restrict__ deg) {
  const int gid = (blockIdx.x + blockIdx.y * gridDim.x) * 256 + threadIdx.x;
  if (gid < NNODES) deg[gid] = 0;

  __shared__ float t[32][33];
  const int n0 = blockIdx.x * 32, k0 = blockIdx.y * 32;
  const int tx = threadIdx.x & 31, ty = threadIdx.x >> 5;  // ty 0..7
  for (int r = ty; r < 32; r += 8)
    t[r][tx] = W[(size_t)(k0 + r) * DDIM + n0 + tx];
  __syncthreads();
  for (int r = ty; r < 32; r += 8)
    Wt[(size_t)(n0 + r) * DDIM + k0 + tx] = f2bf(t[tx][r]);
}

// ---------------------------------------------------------------------------
// MFMA GEMM: C_bf16[M,512] = A_bf16[M,512] @ Wt_bf16[512,512]^T + bias
// 128x128 tile, BK=32, 4 waves (2x2), 16x16x32 MFMA.
// 2-phase double-buffered LDS: STAGE(t+1) issued before COMPUTE(t); one
// vmcnt drain + barrier per K-tile (T3-minimum). global_load_lds staging.
// Both-sides XOR swizzle on staging (source cg / read lk), XCD block swizzle.
// Epilogue: per-wave 64x64 C-tile staged in LDS, coalesced 16B stores.
// ---------------------------------------------------------------------------
__global__ __launch_bounds__(256) void gemm_mfma_kernel(
    const unsigned short* __restrict__ Ab, const unsigned short* __restrict__ Bt,
    const float* __restrict__ bias, unsigned short* __restrict__ C, int M) {
  __shared__ unsigned short As[2][128 * 32];
  __shared__ unsigned short Bs[2][128 * 32];
  const int tid = threadIdx.x;
  const int wid = tid >> 6, lane = tid & 63;

  // bijective XCD-chunked remap (8 XCDs)
  const int nwg = gridDim.x;
  const int q = nwg >> 3, rr = nwg & 7;
  const int x = blockIdx.x & 7, idx = blockIdx.x >> 3;
  const int wg = x * q + min(x, rr) + idx;

  const int mt = wg >> 2, nt = wg & 3;
  const int bm = mt * 128, bn = nt * 128;
  const int wr = wid >> 1, wc = wid & 1;

  f32x4 acc[4][4] = {};

  // staging: slot = tid; row = tid>>2 within half, swizzled col group
  const int r0 = tid >> 2;
  const int cge = (tid & 3) ^ ((r0 >> 1) & 3);

  const int arow0 = min(bm + r0, M - 1);
  const int arow1 = min(bm + r0 + 64, M - 1);

  const unsigned short* a0 = Ab + (size_t)arow0 * DDIM + cge * 8;
  const unsigned short* a1 = Ab + (size_t)arow1 * DDIM + cge * 8;
  const unsigned short* b0 = Bt + (size_t)(bn + r0) * DDIM + cge * 8;
  const unsigned short* b1 = Bt + (size_t)(bn + r0 + 64) * DDIM + cge * 8;

  const int l16 = lane & 15, lk = lane >> 4;
  const int lke = lk ^ ((l16 >> 1) & 3);  // swizzled read k-group

  // wave-uniform LDS staging bases (ushort offsets)
  const int sOff0 = (wid * 64) * 8;
  const int sOff1 = (256 + wid * 64) * 8;

#define STAGE(buf, k0)                        \
  do {                                        \
    gload_lds16(a0 + (k0), &As[buf][sOff0]);  \
    gload_lds16(a1 + (k0), &As[buf][sOff1]);  \
    gload_lds16(b0 + (k0), &Bs[buf][sOff0]);  \
    gload_lds16(b1 + (k0), &Bs[buf][sOff1]);  \
  } while (0)

#define COMPUTE(buf)                                                          \
  do {                                                                        \
    bf16x8 af[4], bfr[4];                                                     \
    _Pragma("unroll") for (int i = 0; i < 4; ++i) {                           \
      af[i]  = *(const bf16x8*)&As[buf][(wr * 64 + i * 16 + l16) * 32 + lke * 8]; \
      bfr[i] = *(const bf16x8*)&Bs[buf][(wc * 64 + i * 16 + l16) * 32 + lke * 8]; \
    }                                                                         \
    _Pragma("unroll") for (int i = 0; i < 4; ++i)                             \
        _Pragma("unroll") for (int j = 0; j < 4; ++j)                         \
            acc[i][j] = __builtin_amdgcn_mfma_f32_16x16x32_bf16(              \
                af[i], bfr[j], acc[i][j], 0, 0, 0);                           \
  } while (0)

  STAGE(0, 0);
  __syncthreads();
#pragma unroll 2
  for (int t = 0; t < 15; ++t) {
    const int cur = t & 1;
    STAGE(cur ^ 1, (t + 1) * 32);  // prefetch next tile into other buffer
    COMPUTE(cur);
    __syncthreads();               // drains vmcnt (prefetch) + lgkm
  }
  COMPUTE(1);       // tile 15 lives in buf 1
  __syncthreads();  // LDS about to be reused as epilogue scratch

  // ---- Epilogue: per-wave 64x64 bf16 tile staged in LDS, coalesced stores.
  unsigned short* cl = (wid < 2) ? &As[0][0] + wid * 4096
                                 : &Bs[0][0] + (wid - 2) * 4096;
#pragma unroll
  for (int j = 0; j < 4; ++j) {
    const float bv = bias[bn + wc * 64 + j * 16 + l16];
#pragma unroll
    for (int i = 0; i < 4; ++i)
#pragma unroll
      for (int qq = 0; qq < 4; ++qq)
        cl[(i * 16 + lk * 4 + qq) * 64 + j * 16 + l16] =
            f2bf(acc[i][j][qq] + bv);
  }
  __syncthreads();
#pragma unroll
  for (int pass = 0; pass < 8; ++pass) {
    const int rt = pass * 8 + (lane >> 3);   // row in 64x64 tile
    const int c0 = (lane & 7) * 8;           // col in 64x64 tile (8 cols/lane)
    const int grow = bm + wr * 64 + rt;
    if (grow < M) {
      const uint4 v = *(const uint4*)&cl[rt * 64 + c0];
      *(uint4*)&C[(size_t)grow * DDIM + bn + wc * 64 + c0] = v;
    }
  }
#undef STAGE
#undef COMPUTE
}

// ---------------------------------------------------------------------------
// CSR build: histogram of dst
// ---------------------------------------------------------------------------
__global__ __launch_bounds__(256) void hist_kernel(const int* __restrict__ dst,
                                                   int* __restrict__ deg, int E) {
  const int e = blockIdx.x * 256 + threadIdx.x;
  if (e < E) atomicAdd(&deg[dst[e]], 1);
}

// ---------------------------------------------------------------------------
// Parallel 3-kernel exclusive scan over deg[0..n) -> off[0..n], cur[0..n)
// ---------------------------------------------------------------------------
__global__ __launch_bounds__(256) void chunk_sum_kernel(
    const int* __restrict__ deg, int* __restrict__ part, int n) {
  const int base = blockIdx.x * 1024;
  int v = 0;
  for (int i = threadIdx.x; i < 1024; i += 256) {
    const int idx = base + i;
    v += (idx < n) ? deg[idx] : 0;
  }
#pragma unroll
  for (int s = 32; s; s >>= 1) v += __shfl_down(v, s, 64);
  __shared__ int ws[4];
  if ((threadIdx.x & 63) == 0) ws[threadIdx.x >> 6] = v;
  __syncthreads();
  if (threadIdx.x == 0) part[blockIdx.x] = ws[0] + ws[1] + ws[2] + ws[3];
}

__global__ void scan_part_kernel(int* __restrict__ part, int nb) {
  const int lane = threadIdx.x & 63;
  int v = (lane < nb) ? part[lane] : 0;
  int incl = v;
#pragma unroll
  for (int s = 1; s < 64; s <<= 1) {
    int t = __shfl_up(incl, s, 64);
    if (lane >= s) incl += t;
  }
  if (lane < nb) part[lane] = incl - v;  // exclusive
}

__global__ __launch_bounds__(1024) void chunk_scan_kernel(
    const int* __restrict__ deg, const int* __restrict__ part,
    int* __restrict__ off, int* __restrict__ cur, int n) {
  __shared__ int wsum[16];
  const int tid = threadIdx.x, lane = tid & 63, wid = tid >> 6;
  const int i = blockIdx.x * 1024 + tid;
  const int v = (i < n) ? deg[i] : 0;
  int incl = v;
#pragma unroll
  for (int s = 1; s < 64; s <<= 1) {
    int t = __shfl_up(incl, s, 64);
    if (lane >= s) incl += t;
  }
  if (lane == 63) wsum[wid] = incl;
  __syncthreads();
  if (wid == 0 && lane < 16) {
    int wv = wsum[lane];
#pragma unroll
    for (int s = 1; s < 16; s <<= 1) {
      int t = __shfl_up(wv, s, 16);
      if (lane >= s) wv += t;
    }
    wsum[lane] = wv;
  }
  __syncthreads();
  const int add = part[blockIdx.x] + ((wid > 0) ? wsum[wid - 1] : 0);
  if (i < n) {
    off[i + 1] = add + incl;
    cur[i] = add + incl - v;
  }
  if (i == 0) off[0] = 0;
}

// ---------------------------------------------------------------------------
// CSR fill: slot per edge via per-dst cursor; pack (src, weight) as uint2.
// ---------------------------------------------------------------------------
__global__ __launch_bounds__(256) void fill_kernel(
    const int* __restrict__ src, const int* __restrict__ dst,
    const float* __restrict__ ew, int* __restrict__ cur,
    uint2* __restrict__ epair, int E) {
  const int e = blockIdx.x * 256 + threadIdx.x;
  if (e >= E) return;
  const int p = atomicAdd(&cur[dst[e]], 1);
  epair[p] = make_uint2((unsigned)src[e], __float_as_uint(ew[e]));
}

// ---------------------------------------------------------------------------
// Gather: one wave per node; 2-deep edge unroll; mean + relu; nontemporal
// row write (out is write-once — keep hp resident in L2/L3).
// ---------------------------------------------------------------------------
__global__ __launch_bounds__(256) void gather_kernel(
    const unsigned short* __restrict__ hp, const int* __restrict__ off,
    const uint2* __restrict__ epair, float* __restrict__ out, int n) {
  const int node = blockIdx.x * 4 + (threadIdx.x >> 6);
  if (node >= n) return;
  const int lane = threadIdx.x & 63;
  const int beg = off[node], end = off[node + 1];

  float acc[8] = {0.f, 0.f, 0.f, 0.f, 0.f, 0.f, 0.f, 0.f};
  int p = beg;
  for (; p + 2 <= end; p += 2) {
    const uint2 e0 = epair[p];
    const uint2 e1 = epair[p + 1];
    const float w0 = __uint_as_float(e0.y);
    const float w1 = __uint_as_float(e1.y);
    const uint4 u0 = *(const uint4*)(hp + (size_t)e0.x * DDIM + lane * 8);
    const uint4 u1 = *(const uint4*)(hp + (size_t)e1.x * DDIM + lane * 8);
    const unsigned a0[4] = {u0.x, u0.y, u0.z, u0.w};
    const unsigned a1[4] = {u1.x, u1.y, u1.z, u1.w};
#pragma unroll
    for (int qv = 0; qv < 4; ++qv) {
      acc[2 * qv + 0] += w0 * __uint_as_float(a0[qv] << 16) +
                         w1 * __uint_as_float(a1[qv] << 16);
      acc[2 * qv + 1] += w0 * __uint_as_float(a0[qv] & 0xffff0000u) +
                         w1 * __uint_as_float(a1[qv] & 0xffff0000u);
    }
  }
  if (p < end) {
    const uint2 e0 = epair[p];
    const float w0 = __uint_as_float(e0.y);
    const uint4 u0 = *(const uint4*)(hp + (size_t)e0.x * DDIM + lane * 8);
    const unsigned a0[4] = {u0.x, u0.y, u0.z, u0.w};
#pragma unroll
    for (int qv = 0; qv < 4; ++qv) {
      acc[2 * qv + 0] += w0 * __uint_as_float(a0[qv] << 16);
      acc[2 * qv + 1] += w0 * __uint_as_float(a0[qv] & 0xffff0000u);
    }
  }

  const float inv = 1.0f / fmaxf((float)(end - beg), 1.0f);
  f32x4 o0, o1;
  o0.x = fmaxf(acc[0] * inv, 0.f);
  o0.y = fmaxf(acc[1] * inv, 0.f);
  o0.z = fmaxf(acc[2] * inv, 0.f);
  o0.w = fmaxf(acc[3] * inv, 0.f);
  o1.x = fmaxf(acc[4] * inv, 0.f);
  o1.y = fmaxf(acc[5] * inv, 0.f);
  o1.z = fmaxf(acc[6] * inv, 0.f);
  o1.w = fmaxf(acc[7] * inv, 0.f);
  float* orow = out + (size_t)node * DDIM + lane * 8;
  __builtin_nontemporal_store(o0, (f32x4*)(orow + 0));
  __builtin_nontemporal_store(o1, (f32x4*)(orow + 4));
}

extern "C" void kernel_launch(void* const* d_in, const int* in_sizes, int n_in,
                              void* d_out, int out_size, void* d_ws, size_t ws_size,
                              hipStream_t stream) {
  const float* h  = (const float*)d_in[0];
  const float* W  = (const float*)d_in[1];
  const float* b  = (const float*)d_in[2];
  const float* ew = (const float*)d_in[3];
  const int* src  = (const int*)d_in[4];
  const int* dst  = (const int*)d_in[5];
  float* out = (float*)d_out;

  // bf16 h and Wt live in d_out (dead before gather overwrites d_out fully)
  unsigned short* hb = (unsigned short*)d_out;                                      // 51.2 MB
  unsigned short* Wt = (unsigned short*)((char*)d_out + (size_t)NNODES * DDIM * 2); // 0.5 MB

  // Workspace: hp (bf16 h_proj) + CSR arrays
  char* ws = (char*)d_ws;
  size_t o = 0;
  auto alloc = [&](size_t bytes) {
    char* p = ws + o;
    o += (bytes + 255) & ~(size_t)255;
    return p;
  };
  unsigned short* hp = (unsigned short*)alloc((size_t)NNODES * DDIM * 2);  // 51.2 MB
  int* deg    = (int*)alloc((size_t)NNODES * 4);
  int* off    = (int*)alloc((size_t)(NNODES + 1) * 4);
  int* cur    = (int*)alloc((size_t)NNODES * 4);
  uint2* epair = (uint2*)alloc((size_t)NEDGES * 8);
  int* part   = (int*)alloc(64 * 4);

  const int nchunks = (NNODES + 1023) / 1024;  // 49

  // 1) fp32 -> bf16 conversions (cvt_wt also zeros deg[])
  cvt_h_kernel<<<2048, 256, 0, stream>>>(h, hb, NNODES * DDIM / 8);
  dim3 wgrid(16, 16);
  cvt_wt_kernel<<<wgrid, 256, 0, stream>>>(W, Wt, deg);

  // 2) MFMA GEMM: hp = bf16(hb @ Wt^T + b)
  const int mtiles = (NNODES + 127) / 128;  // 391
  gemm_mfma_kernel<<<mtiles * 4, 256, 0, stream>>>(hb, Wt, b, hp, NNODES);

  // 3) CSR build by dst (parallel scan)
  hist_kernel<<<(NEDGES + 255) / 256, 256, 0, stream>>>(dst, deg, NEDGES);
  chunk_sum_kernel<<<nchunks, 256, 0, stream>>>(deg, part, NNODES);
  scan_part_kernel<<<1, 64, 0, stream>>>(part, nchunks);
  chunk_scan_kernel<<<nchunks, 1024, 0, stream>>>(deg, part, off, cur, NNODES);
  fill_kernel<<<(NEDGES + 255) / 256, 256, 0, stream>>>(src, dst, ew, cur,
                                                        epair, NEDGES);

  // 4) Gather + mean + relu (one wave per node)
  gather_kernel<<<(NNODES + 3) / 4, 256, 0, stream>>>(hp, off, epair, out,
                                                      NNODES);
}

// Round 10
// 137.968 us; speedup vs baseline: 1.1224x; 1.0957x over previous
//
#include <hip/hip_runtime.h>

#define NNODES 50000
#define NEDGES 200000
#define DDIM 512

typedef __attribute__((ext_vector_type(8))) short bf16x8;
typedef __attribute__((ext_vector_type(4))) float f32x4;

static __device__ __forceinline__ unsigned short f2bf(float f) {
  unsigned u = __float_as_uint(f);
  unsigned r = (u + 0x7fffu + ((u >> 16) & 1u)) >> 16;  // RNE
  return (unsigned short)r;
}

static __device__ __forceinline__ void gload_lds16(const void* g, void* l) {
  __builtin_amdgcn_global_load_lds(
      (const __attribute__((address_space(1))) unsigned int*)g,
      (__attribute__((address_space(3))) unsigned int*)l, 16, 0, 0);
}

// 8 fp32 -> bf16x8 via hardware v_cvt_pk_bf16_f32 (RNE, matches f2bf)
static __device__ __forceinline__ bf16x8 cvt_frag(f32x4 lo, f32x4 hi) {
  union { bf16x8 v; unsigned u[4]; } r;
  asm("v_cvt_pk_bf16_f32 %0, %1, %2" : "=v"(r.u[0]) : "v"(lo.x), "v"(lo.y));
  asm("v_cvt_pk_bf16_f32 %0, %1, %2" : "=v"(r.u[1]) : "v"(lo.z), "v"(lo.w));
  asm("v_cvt_pk_bf16_f32 %0, %1, %2" : "=v"(r.u[2]) : "v"(hi.x), "v"(hi.y));
  asm("v_cvt_pk_bf16_f32 %0, %1, %2" : "=v"(r.u[3]) : "v"(hi.z), "v"(hi.w));
  return r.v;
}

// ---------------------------------------------------------------------------
// Wt[n][k] = bf16(W[k][n])  (512x512 transpose via LDS) + zero deg[]
// ---------------------------------------------------------------------------
__global__ __launch_bounds__(256) void cvt_wt_kernel(
    const float* __restrict__ W, unsigned short* __restrict__ Wt,
    int* __restrict__ deg) {
  const int gid = (blockIdx.x + blockIdx.y * gridDim.x) * 256 + threadIdx.x;
  if (gid < NNODES) deg[gid] = 0;

  __shared__ float t[32][33];
  const int n0 = blockIdx.x * 32, k0 = blockIdx.y * 32;
  const int tx = threadIdx.x & 31, ty = threadIdx.x >> 5;  // ty 0..7
  for (int r = ty; r < 32; r += 8)
    t[r][tx] = W[(size_t)(k0 + r) * DDIM + n0 + tx];
  __syncthreads();
  for (int r = ty; r < 32; r += 8)
    Wt[(size_t)(n0 + r) * DDIM + k0 + tx] = f2bf(t[tx][r]);
}

// ---------------------------------------------------------------------------
// MFMA GEMM: C_bf16[M,512] = bf16(A_f32[M,512]) @ Wt_bf16[512,512]^T + bias
// 128x128 tile, BK=32, 4 waves (2x2), 16x16x32 MFMA.
// A staged as RAW FP32 via async global_load_lds (16KB/buf, 4 loads/thread);
// fp32->bf16 happens on the fragment-read path with v_cvt_pk_bf16_f32
// (hardware, 16 instrs per 16 MFMAs — NOT round 8's sw-RNE + ds_write).
// A swizzle: 16B-kquad ^= row&7 (both-sides: pre-swizzled global source
// per lane + swizzled ds_read offset). B unchanged bf16 path.
// 2-phase double buffer; XCD-chunked block swizzle; LDS-staged epilogue.
// ---------------------------------------------------------------------------
__global__ __launch_bounds__(256) void gemm_mfma_kernel(
    const float* __restrict__ A, const unsigned short* __restrict__ Bt,
    const float* __restrict__ bias, unsigned short* __restrict__ C, int M) {
  __shared__ float Af[2][128 * 32];          // 2 x 16 KB (fp32 A tile)
  __shared__ unsigned short Bs[2][128 * 32]; // 2 x 8 KB  (bf16 B tile)
  const int tid = threadIdx.x;
  const int wid = tid >> 6, lane = tid & 63;

  // bijective XCD-chunked remap (8 XCDs)
  const int nwg = gridDim.x;
  const int q = nwg >> 3, rr = nwg & 7;
  const int x = blockIdx.x & 7, idx = blockIdx.x >> 3;
  const int wg = x * q + min(x, rr) + idx;

  const int mt = wg >> 2, nt = wg & 3;
  const int bm = mt * 128, bn = nt * 128;
  const int wr = wid >> 1, wc = wid & 1;

  f32x4 acc[4][4] = {};

  // ---- A staging geometry: slot s = c*256 + wid*64 + lane (16B = 4 f32)
  //      phys row = s>>3 (8 kquads/row), phys kquad = lane&7.
  //      source kquad = phys ^ (row&7); row&7 == lane>>3.
  const int lr = lane >> 3;                  // 0..7
  const int kqs = (lane & 7) ^ lr;           // swizzled source kquad
  const int ar0 = min(bm + 0 * 32 + wid * 8 + lr, M - 1);
  const int ar1 = min(bm + 1 * 32 + wid * 8 + lr, M - 1);
  const int ar2 = min(bm + 2 * 32 + wid * 8 + lr, M - 1);
  const int ar3 = min(bm + 3 * 32 + wid * 8 + lr, M - 1);
  const float* pa0 = A + (size_t)ar0 * DDIM + kqs * 4;
  const float* pa1 = A + (size_t)ar1 * DDIM + kqs * 4;
  const float* pa2 = A + (size_t)ar2 * DDIM + kqs * 4;
  const float* pa3 = A + (size_t)ar3 * DDIM + kqs * 4;

  // ---- B staging (unchanged from verified round-5 kernel)
  const int r0 = tid >> 2;
  const int cge = (tid & 3) ^ ((r0 >> 1) & 3);
  const unsigned short* b0 = Bt + (size_t)(bn + r0) * DDIM + cge * 8;
  const unsigned short* b1 = Bt + (size_t)(bn + r0 + 64) * DDIM + cge * 8;

  const int l16 = lane & 15, lk = lane >> 4;
  const int lke = lk ^ ((l16 >> 1) & 3);     // B swizzled read k-group
  const int s7 = l16 & 7;                    // A read-side row&7

  const int sOff0 = (wid * 64) * 8;          // B LDS bases (ushort units)
  const int sOff1 = (256 + wid * 64) * 8;

#define STAGE(buf, k0)                                   \
  do {                                                   \
    gload_lds16(pa0 + (k0), &Af[buf][wid * 256]);        \
    gload_lds16(pa1 + (k0), &Af[buf][1024 + wid * 256]); \
    gload_lds16(pa2 + (k0), &Af[buf][2048 + wid * 256]); \
    gload_lds16(pa3 + (k0), &Af[buf][3072 + wid * 256]); \
    gload_lds16(b0 + (k0), &Bs[buf][sOff0]);             \
    gload_lds16(b1 + (k0), &Bs[buf][sOff1]);             \
  } while (0)

#define COMPUTE(buf)                                                          \
  do {                                                                        \
    bf16x8 af[4], bfr[4];                                                     \
    _Pragma("unroll") for (int i = 0; i < 4; ++i) {                           \
      const int rowi = (wr * 64 + i * 16 + l16) * 32;                         \
      const f32x4 lo = *(const f32x4*)&Af[buf][rowi + (((2 * lk) ^ s7) << 2)];\
      const f32x4 hi = *(const f32x4*)&Af[buf][rowi + (((2 * lk + 1) ^ s7) << 2)]; \
      af[i] = cvt_frag(lo, hi);                                               \
      bfr[i] = *(const bf16x8*)&Bs[buf][(wc * 64 + i * 16 + l16) * 32 + lke * 8]; \
    }                                                                         \
    _Pragma("unroll") for (int i = 0; i < 4; ++i)                             \
        _Pragma("unroll") for (int j = 0; j < 4; ++j)                         \
            acc[i][j] = __builtin_amdgcn_mfma_f32_16x16x32_bf16(              \
                af[i], bfr[j], acc[i][j], 0, 0, 0);                           \
  } while (0)

  STAGE(0, 0);
  __syncthreads();
#pragma unroll 2
  for (int t = 0; t < 15; ++t) {
    const int cur = t & 1;
    STAGE(cur ^ 1, (t + 1) * 32);  // prefetch next tile into other buffer
    COMPUTE(cur);
    __syncthreads();               // drains vmcnt (prefetch) + lgkm
  }
  COMPUTE(1);       // tile 15 lives in buf 1
  __syncthreads();  // LDS about to be reused as epilogue scratch

  // ---- Epilogue: per-wave 64x64 bf16 tile staged in LDS, coalesced stores.
  unsigned short* cl = (unsigned short*)&Af[0][0] + wid * 4096;
#pragma unroll
  for (int j = 0; j < 4; ++j) {
    const float bv = bias[bn + wc * 64 + j * 16 + l16];
#pragma unroll
    for (int i = 0; i < 4; ++i)
#pragma unroll
      for (int qq = 0; qq < 4; ++qq)
        cl[(i * 16 + lk * 4 + qq) * 64 + j * 16 + l16] =
            f2bf(acc[i][j][qq] + bv);
  }
  __syncthreads();
#pragma unroll
  for (int pass = 0; pass < 8; ++pass) {
    const int rt = pass * 8 + (lane >> 3);   // row in 64x64 tile
    const int c0 = (lane & 7) * 8;           // col in 64x64 tile (8 cols/lane)
    const int grow = bm + wr * 64 + rt;
    if (grow < M) {
      const uint4 v = *(const uint4*)&cl[rt * 64 + c0];
      *(uint4*)&C[(size_t)grow * DDIM + bn + wc * 64 + c0] = v;
    }
  }
#undef STAGE
#undef COMPUTE
}

// ---------------------------------------------------------------------------
// CSR build: histogram of dst
// ---------------------------------------------------------------------------
__global__ __launch_bounds__(256) void hist_kernel(const int* __restrict__ dst,
                                                   int* __restrict__ deg, int E) {
  const int e = blockIdx.x * 256 + threadIdx.x;
  if (e < E) atomicAdd(&deg[dst[e]], 1);
}

// ---------------------------------------------------------------------------
// Parallel 3-kernel exclusive scan over deg[0..n) -> off[0..n], cur[0..n)
// ---------------------------------------------------------------------------
__global__ __launch_bounds__(256) void chunk_sum_kernel(
    const int* __restrict__ deg, int* __restrict__ part, int n) {
  const int base = blockIdx.x * 1024;
  int v = 0;
  for (int i = threadIdx.x; i < 1024; i += 256) {
    const int idx = base + i;
    v += (idx < n) ? deg[idx] : 0;
  }
#pragma unroll
  for (int s = 32; s; s >>= 1) v += __shfl_down(v, s, 64);
  __shared__ int ws[4];
  if ((threadIdx.x & 63) == 0) ws[threadIdx.x >> 6] = v;
  __syncthreads();
  if (threadIdx.x == 0) part[blockIdx.x] = ws[0] + ws[1] + ws[2] + ws[3];
}

__global__ void scan_part_kernel(int* __restrict__ part, int nb) {
  const int lane = threadIdx.x & 63;
  int v = (lane < nb) ? part[lane] : 0;
  int incl = v;
#pragma unroll
  for (int s = 1; s < 64; s <<= 1) {
    int t = __shfl_up(incl, s, 64);
    if (lane >= s) incl += t;
  }
  if (lane < nb) part[lane] = incl - v;  // exclusive
}

__global__ __launch_bounds__(1024) void chunk_scan_kernel(
    const int* __restrict__ deg, const int* __restrict__ part,
    int* __restrict__ off, int* __restrict__ cur, int n) {
  __shared__ int wsum[16];
  const int tid = threadIdx.x, lane = tid & 63, wid = tid >> 6;
  const int i = blockIdx.x * 1024 + tid;
  const int v = (i < n) ? deg[i] : 0;
  int incl = v;
#pragma unroll
  for (int s = 1; s < 64; s <<= 1) {
    int t = __shfl_up(incl, s, 64);
    if (lane >= s) incl += t;
  }
  if (lane == 63) wsum[wid] = incl;
  __syncthreads();
  if (wid == 0 && lane < 16) {
    int wv = wsum[lane];
#pragma unroll
    for (int s = 1; s < 16; s <<= 1) {
      int t = __shfl_up(wv, s, 16);
      if (lane >= s) wv += t;
    }
    wsum[lane] = wv;
  }
  __syncthreads();
  const int add = part[blockIdx.x] + ((wid > 0) ? wsum[wid - 1] : 0);
  if (i < n) {
    off[i + 1] = add + incl;
    cur[i] = add + incl - v;
  }
  if (i == 0) off[0] = 0;
}

// ---------------------------------------------------------------------------
// CSR fill: slot per edge via per-dst cursor; pack (src, weight) as uint2.
// ---------------------------------------------------------------------------
__global__ __launch_bounds__(256) void fill_kernel(
    const int* __restrict__ src, const int* __restrict__ dst,
    const float* __restrict__ ew, int* __restrict__ cur,
    uint2* __restrict__ epair, int E) {
  const int e = blockIdx.x * 256 + threadIdx.x;
  if (e >= E) return;
  const int p = atomicAdd(&cur[dst[e]], 1);
  epair[p] = make_uint2((unsigned)src[e], __float_as_uint(ew[e]));
}

// ---------------------------------------------------------------------------
// Gather: one wave per node; 2-deep edge unroll; mean + relu; nontemporal
// row write (out is write-once — keep hp resident in L2/L3).
// ---------------------------------------------------------------------------
__global__ __launch_bounds__(256) void gather_kernel(
    const unsigned short* __restrict__ hp, const int* __restrict__ off,
    const uint2* __restrict__ epair, float* __restrict__ out, int n) {
  const int node = blockIdx.x * 4 + (threadIdx.x >> 6);
  if (node >= n) return;
  const int lane = threadIdx.x & 63;
  const int beg = off[node], end = off[node + 1];

  float acc[8] = {0.f, 0.f, 0.f, 0.f, 0.f, 0.f, 0.f, 0.f};
  int p = beg;
  for (; p + 2 <= end; p += 2) {
    const uint2 e0 = epair[p];
    const uint2 e1 = epair[p + 1];
    const float w0 = __uint_as_float(e0.y);
    const float w1 = __uint_as_float(e1.y);
    const uint4 u0 = *(const uint4*)(hp + (size_t)e0.x * DDIM + lane * 8);
    const uint4 u1 = *(const uint4*)(hp + (size_t)e1.x * DDIM + lane * 8);
    const unsigned a0[4] = {u0.x, u0.y, u0.z, u0.w};
    const unsigned a1[4] = {u1.x, u1.y, u1.z, u1.w};
#pragma unroll
    for (int qv = 0; qv < 4; ++qv) {
      acc[2 * qv + 0] += w0 * __uint_as_float(a0[qv] << 16) +
                         w1 * __uint_as_float(a1[qv] << 16);
      acc[2 * qv + 1] += w0 * __uint_as_float(a0[qv] & 0xffff0000u) +
                         w1 * __uint_as_float(a1[qv] & 0xffff0000u);
    }
  }
  if (p < end) {
    const uint2 e0 = epair[p];
    const float w0 = __uint_as_float(e0.y);
    const uint4 u0 = *(const uint4*)(hp + (size_t)e0.x * DDIM + lane * 8);
    const unsigned a0[4] = {u0.x, u0.y, u0.z, u0.w};
#pragma unroll
    for (int qv = 0; qv < 4; ++qv) {
      acc[2 * qv + 0] += w0 * __uint_as_float(a0[qv] << 16);
      acc[2 * qv + 1] += w0 * __uint_as_float(a0[qv] & 0xffff0000u);
    }
  }

  const float inv = 1.0f / fmaxf((float)(end - beg), 1.0f);
  f32x4 o0, o1;
  o0.x = fmaxf(acc[0] * inv, 0.f);
  o0.y = fmaxf(acc[1] * inv, 0.f);
  o0.z = fmaxf(acc[2] * inv, 0.f);
  o0.w = fmaxf(acc[3] * inv, 0.f);
  o1.x = fmaxf(acc[4] * inv, 0.f);
  o1.y = fmaxf(acc[5] * inv, 0.f);
  o1.z = fmaxf(acc[6] * inv, 0.f);
  o1.w = fmaxf(acc[7] * inv, 0.f);
  float* orow = out + (size_t)node * DDIM + lane * 8;
  __builtin_nontemporal_store(o0, (f32x4*)(orow + 0));
  __builtin_nontemporal_store(o1, (f32x4*)(orow + 4));
}

extern "C" void kernel_launch(void* const* d_in, const int* in_sizes, int n_in,
                              void* d_out, int out_size, void* d_ws, size_t ws_size,
                              hipStream_t stream) {
  const float* h  = (const float*)d_in[0];
  const float* W  = (const float*)d_in[1];
  const float* b  = (const float*)d_in[2];
  const float* ew = (const float*)d_in[3];
  const int* src  = (const int*)d_in[4];
  const int* dst  = (const int*)d_in[5];
  float* out = (float*)d_out;

  // Workspace: hp (bf16 h_proj), Wt, CSR arrays
  char* ws = (char*)d_ws;
  size_t o = 0;
  auto alloc = [&](size_t bytes) {
    char* p = ws + o;
    o += (bytes + 255) & ~(size_t)255;
    return p;
  };
  unsigned short* hp = (unsigned short*)alloc((size_t)NNODES * DDIM * 2);  // 51.2 MB
  unsigned short* Wt = (unsigned short*)alloc((size_t)DDIM * DDIM * 2);    // 0.5 MB
  int* deg    = (int*)alloc((size_t)NNODES * 4);
  int* off    = (int*)alloc((size_t)(NNODES + 1) * 4);
  int* cur    = (int*)alloc((size_t)NNODES * 4);
  uint2* epair = (uint2*)alloc((size_t)NEDGES * 8);
  int* part   = (int*)alloc(64 * 4);

  const int nchunks = (NNODES + 1023) / 1024;  // 49

  // 1) W transpose+cvt (also zeros deg[])
  dim3 wgrid(16, 16);
  cvt_wt_kernel<<<wgrid, 256, 0, stream>>>(W, Wt, deg);

  // 2) MFMA GEMM (reads fp32 h directly): hp = bf16(bf16(h) @ Wt^T + b)
  const int mtiles = (NNODES + 127) / 128;  // 391
  gemm_mfma_kernel<<<mtiles * 4, 256, 0, stream>>>(h, Wt, b, hp, NNODES);

  // 3) CSR build by dst (parallel scan)
  hist_kernel<<<(NEDGES + 255) / 256, 256, 0, stream>>>(dst, deg, NEDGES);
  chunk_sum_kernel<<<nchunks, 256, 0, stream>>>(deg, part, NNODES);
  scan_part_kernel<<<1, 64, 0, stream>>>(part, nchunks);
  chunk_scan_kernel<<<nchunks, 1024, 0, stream>>>(deg, part, off, cur, NNODES);
  fill_kernel<<<(NEDGES + 255) / 256, 256, 0, stream>>>(src, dst, ew, cur,
                                                        epair, NEDGES);

  // 4) Gather + mean + relu (one wave per node)
  gather_kernel<<<(NNODES + 3) / 4, 256, 0, stream>>>(hp, off, epair, out,
                                                      NNODES);
}